// Round 13
// baseline (24.504 us; speedup 1.0000x reference)
//
#include <hip/hip_runtime.h>

#define BATCH  4096
#define TLEN   750
#define NK     6                 // pair offsets k=1..6 (k=0 contributes exactly 0)
#define WSTRIP 250               // owned columns per strip
#define NSTRIP 3                 // 3*250 = 750 exactly
#define NTH1   768               // 12 waves = 3 strips x 4 row-subsets
#define RSUB   4                 // row-subsets per block
#define NGR    512               // row-groups == K1 grid (2 blocks/CU, balanced)
#define RPB    (BATCH/NGR)       // 8 rows per block
#define RPW    (RPB/RSUB)        // 2 rows per wave
#define QSZ    (2*NK*256)        // 3072 floats per strip partial (LDS)
#define NJ     (NSTRIP*NK*2)     // 36 pair-slabs (strip, k, half)
#define NTH2   1024              // K2 block size

// ---------------- helpers ----------------

template<int NW>
__device__ __forceinline__ float block_reduce(float v, float* red) {
    #pragma unroll
    for (int off = 32; off > 0; off >>= 1) v += __shfl_down(v, off, 64);
    const int t = threadIdx.x;
    if ((t & 63) == 0) red[t >> 6] = v;
    __syncthreads();
    float r = 0.f;
    if (t == 0) {
        #pragma unroll
        for (int w = 0; w < NW; ++w) r += red[w];
    }
    __syncthreads();
    return r;
}

// pack two non-negative finite floats as bf16 pair (RNE-ish) into one u32
__device__ __forceinline__ unsigned pack2(float v1, float v2) {
    const unsigned b1 = (__float_as_uint(v1) + 0x8000u) >> 16;
    const unsigned b2 = (__float_as_uint(v2) + 0x8000u) >> 16;
    return (b1 << 16) | (b2 & 0xffffu);
}

// ---------------- K1: two balanced blocks per CU ----------------
// Wave w: strip s = w%3, row-subset rw = w/3 (2 rows). Lane owns 4 cols via
// two float2 loads (even bases -> 8B aligned; min(...,748) clamps at array
// end). All 8 loads of the 2-row batch are issued before any dependent op.
// Neighborhood n[0..9]: 4 shuffles from lane+1, 2 from lane+2 per array.
// Garbage reaches only slots with strip-local q>=250 or i+k>749 -- K2 gates.
// Partials stored TRANSPOSED + bf16-PACKED: pu[((s*12+2k+h)*NGR+g)*128 + idx],
// u32 = (bf16(S1)<<16)|bf16(S2), h=col>>7, idx=col&127.
__global__ __launch_bounds__(NTH1, 6) void actloss_k1(
        const float* __restrict__ a, const float* __restrict__ a2,
        unsigned* __restrict__ pu, float* __restrict__ resp) {
    const int t  = threadIdx.x;
    const int w  = t >> 6;
    const int l  = t & 63;
    const int s  = w % NSTRIP;
    const int rw = w / NSTRIP;
    const int g  = (int)blockIdx.x;

    const int colr = s * WSTRIP + 4 * l;
    const int bc0  = min(colr,     TLEN - 2);
    const int bc1  = min(colr + 2, TLEN - 2);

    float maskf[4];
    #pragma unroll
    for (int c = 0; c < 4; ++c) maskf[c] = (4 * l + c < WSTRIP) ? 1.f : 0.f;

    float s1[4][NK], s2[4][NK];
    #pragma unroll
    for (int c = 0; c < 4; ++c)
        #pragma unroll
        for (int k = 0; k < NK; ++k) { s1[c][k] = 0.f; s2[c][k] = 0.f; }
    float res = 0.f;

    const int r0 = g * RPB + rw * RPW;

    // ---- issue ALL loads of the 2-row batch up front (8 float2 in flight) --
    float2 A0[RPW], A1[RPW], B0[RPW], B1[RPW];
    #pragma unroll
    for (int r = 0; r < RPW; ++r) {
        const size_t off = (size_t)(r0 + r) * TLEN;
        A0[r] = *reinterpret_cast<const float2*>(a  + off + bc0);
        A1[r] = *reinterpret_cast<const float2*>(a  + off + bc1);
        B0[r] = *reinterpret_cast<const float2*>(a2 + off + bc0);
        B1[r] = *reinterpret_cast<const float2*>(a2 + off + bc1);
    }

    #pragma unroll
    for (int r = 0; r < RPW; ++r) {
        float n[10], m[10];
        n[0] = A0[r].x; n[1] = A0[r].y; n[2] = A1[r].x; n[3] = A1[r].y;
        m[0] = B0[r].x; m[1] = B0[r].y; m[2] = B1[r].x; m[3] = B1[r].y;
        #pragma unroll
        for (int j = 0; j < 4; ++j) {
            n[4 + j] = __shfl_down(n[j], 1, 64);
            m[4 + j] = __shfl_down(m[j], 1, 64);
        }
        n[8] = __shfl_down(n[0], 2, 64);  n[9] = __shfl_down(n[1], 2, 64);
        m[8] = __shfl_down(m[0], 2, 64);  m[9] = __shfl_down(m[1], 2, 64);

        #pragma unroll
        for (int c = 0; c < 4; ++c) {
            #pragma unroll
            for (int k = 1; k <= NK; ++k) {
                const float d = n[c] - n[c + k];
                s1[c][k - 1] = fmaf(d, d, s1[c][k - 1]);
                s2[c][k - 1] += fabsf(m[c] - m[c + k]);
            }
            const float rr = n[c] - m[c];
            res = fmaf(rr * rr, maskf[c], res);
        }
    }

    // staged cross-subset reduce: rw==0 writes, rw==1..3 add (barrier-phased)
    __shared__ float buf[NSTRIP][QSZ];    // 36 KB (x2 blocks/CU = 72 KB)
    __shared__ float rwred[12];
    if (rw == 0) {
        #pragma unroll
        for (int k = 0; k < NK; ++k) {
            *reinterpret_cast<float4*>(&buf[s][k * 256 + 4 * l]) =
                make_float4(s1[0][k], s1[1][k], s1[2][k], s1[3][k]);
            *reinterpret_cast<float4*>(&buf[s][NK * 256 + k * 256 + 4 * l]) =
                make_float4(s2[0][k], s2[1][k], s2[2][k], s2[3][k]);
        }
    }
    #pragma unroll
    for (int off = 32; off > 0; off >>= 1) res += __shfl_down(res, off, 64);
    if (l == 0) rwred[w] = res;
    __syncthreads();
    #pragma unroll
    for (int stage = 1; stage < RSUB; ++stage) {
        if (rw == stage) {
            #pragma unroll
            for (int k = 0; k < NK; ++k) {
                float4* q1 = reinterpret_cast<float4*>(&buf[s][k * 256 + 4 * l]);
                float4 v1 = *q1;
                v1.x += s1[0][k]; v1.y += s1[1][k]; v1.z += s1[2][k]; v1.w += s1[3][k];
                *q1 = v1;
                float4* q2 = reinterpret_cast<float4*>(&buf[s][NK * 256 + k * 256 + 4 * l]);
                float4 v2 = *q2;
                v2.x += s2[0][k]; v2.y += s2[1][k]; v2.z += s2[2][k]; v2.w += s2[3][k];
                *q2 = v2;
            }
        }
        __syncthreads();
    }

    // packed transposed store: 4608 u32 per block, 6 iterations
    for (int e = t; e < NSTRIP * NK * 256; e += NTH1) {
        const int si  = e / (NK * 256);
        const int rem = e % (NK * 256);
        const int k   = rem >> 8;
        const int col = rem & 255;
        const int h   = col >> 7;
        const int idx = col & 127;
        const unsigned pk = pack2(buf[si][k * 256 + col],
                                  buf[si][NK * 256 + k * 256 + col]);
        pu[((size_t)(si * 12 + (k << 1) + h) * NGR + g) * 128 + idx] = pk;
    }
    if (t == 0) {
        float rs = 0.f;
        #pragma unroll
        for (int i = 0; i < 12; ++i) rs += rwred[i];
        resp[g] = rs;
    }
}

// ---------------- K2: streaming packed g-sum + in-block finish ----------------
// Block j streams its contiguous 256 KB slab with uint4, unpacks bf16 pairs,
// accumulates f32, transposes via LDS, applies exp + closed-form weight:
//   base (k<=4 ? 2 : 1); +(6-k) at i=0; +(4-k) at i=749-k (k<=3).
// Block 0 additionally reduces the res partials into partial[36].
__global__ __launch_bounds__(NTH2) void actloss_k2(
        const unsigned* __restrict__ pu, const float* __restrict__ resp,
        float* __restrict__ partial) {
    const int t = threadIdx.x;
    const int j = (int)blockIdx.x;
    const uint4* slab = reinterpret_cast<const uint4*>(pu + (size_t)j * NGR * 128);

    const int cg    = t & 31;    // colgroup: cols 4cg..4cg+3
    const int gbase = t >> 5;    // 0..31

    float s1a[4] = {0.f, 0.f, 0.f, 0.f}, s2a[4] = {0.f, 0.f, 0.f, 0.f};
    #pragma unroll
    for (int pass = 0; pass < NGR / 32; ++pass) {          // 16 passes
        const uint4 v = slab[(size_t)(pass * 32 + gbase) * 32 + cg];
        const unsigned u[4] = {v.x, v.y, v.z, v.w};
        #pragma unroll
        for (int c = 0; c < 4; ++c) {
            s1a[c] += __uint_as_float(u[c] & 0xffff0000u);
            s2a[c] += __uint_as_float(u[c] << 16);
        }
    }

    __shared__ float smA[NTH2][5], smB[NTH2][5];   // pad 5: conflict-free writes
    __shared__ float red[16];
    #pragma unroll
    for (int c = 0; c < 4; ++c) { smA[t][c] = s1a[c]; smB[t][c] = s2a[c]; }
    __syncthreads();

    float acc = 0.f;
    if (t < 128) {
        float S1 = 0.f, S2 = 0.f;
        const int rcg = t >> 2, ci = t & 3;
        #pragma unroll
        for (int q = 0; q < 32; ++q) {
            S1 += smA[q * 32 + rcg][ci];
            S2 += smB[q * 32 + rcg][ci];
        }
        const int s  = j / 12;
        const int jj = j % 12;
        const int k1 = (jj >> 1) + 1;
        const int h  = jj & 1;
        const int col = h * 128 + t;
        const int i   = s * WSTRIP + col;
        if (col < WSTRIP && i + k1 <= TLEN - 1) {
            const float Tv = expf(-0.5f * S1) * S2;
            float wgt = (k1 <= 4) ? 2.f : 1.f;
            if (i == 0) wgt += (float)(6 - k1);
            if (k1 <= 3 && i == TLEN - 1 - k1) wgt += (float)(4 - k1);
            acc = wgt * Tv;
        }
    }
    const float r = block_reduce<16>(acc, red);
    if (t == 0) partial[j] = r;

    if (j == 0) {   // block-uniform: fold res reduction into K2
        const float ra = (t < NGR) ? resp[t] : 0.f;
        const float r2 = block_reduce<16>(ra, red);
        if (t == 0) partial[NJ] = r2;
    }
}

// ---------------- K3: single-wave scalar finish ----------------
__global__ __launch_bounds__(64) void actloss_k3(
        const float* __restrict__ partial, float* __restrict__ out) {
    const int t = threadIdx.x;
    float v = (t < NJ) ? partial[t] : 0.f;
    if (t == 0) v += 0.1f * partial[NJ];
    #pragma unroll
    for (int off = 32; off > 0; off >>= 1) v += __shfl_down(v, off, 64);
    if (t == 0) out[0] = v * (1.0f / (float)BATCH);
}

// ---------------- fallback slow path (round-1, known-good) ----------------

__global__ __launch_bounds__(256) void actloss_col_kernel(
        const float* __restrict__ a, const float* __restrict__ a2,
        float* __restrict__ part) {
    const int i = blockIdx.x;
    const int t = threadIdx.x;
    __shared__ float red[4];
    int cidx[11];
    #pragma unroll
    for (int j = 0; j < 11; ++j) {
        int c = i + j - 6;
        cidx[j] = c < 0 ? 0 : (c > TLEN - 1 ? TLEN - 1 : c);
    }
    float s1[11], s2[11];
    #pragma unroll
    for (int j = 0; j < 11; ++j) { s1[j] = 0.f; s2[j] = 0.f; }
    float resacc = 0.f;
    for (int b = t; b < BATCH; b += 256) {
        const float* arow  = a  + (size_t)b * TLEN;
        const float* a2row = a2 + (size_t)b * TLEN;
        const float ai = arow[i], a2i = a2row[i];
        const float r = ai - a2i;
        resacc = fmaf(r, r, resacc);
        #pragma unroll
        for (int j = 0; j < 11; ++j) {
            const float d = ai - arow[cidx[j]];
            s1[j] = fmaf(d, d, s1[j]);
            s2[j] += fabsf(a2i - a2row[cidx[j]]);
        }
    }
    float term = 0.f;
    #pragma unroll
    for (int j = 0; j < 11; ++j) {
        const float s1r = block_reduce<4>(s1[j], red);
        const float s2r = block_reduce<4>(s2[j], red);
        if (t == 0) term += expf(-0.5f * s1r) * s2r;
    }
    const float resr = block_reduce<4>(resacc, red);
    if (t == 0) part[i] = (term + 0.1f * resr) * (1.0f / (float)BATCH);
}

__global__ __launch_bounds__(256) void actloss_fallback_reduce(
        const float* __restrict__ part, float* __restrict__ out) {
    __shared__ float red[4];
    float v = 0.f;
    for (int k = threadIdx.x; k < TLEN; k += 256) v += part[k];
    const float r = block_reduce<4>(v, red);
    if (threadIdx.x == 0) out[0] = r;
}

// ---------------- launcher ----------------

extern "C" void kernel_launch(void* const* d_in, const int* in_sizes, int n_in,
                              void* d_out, int out_size, void* d_ws, size_t ws_size,
                              hipStream_t stream) {
    const float* a  = (const float*)d_in[0];   // actioness
    const float* a2 = (const float*)d_in[1];   // actioness_2
    float* out = (float*)d_out;

    const size_t puN  = (size_t)NJ * NGR * 128;       // 2,359,296 u32 (9.4 MB)
    const size_t need = (puN + 64 + NGR + 16) * 4;

    if (ws_size >= need) {
        unsigned* pu      = (unsigned*)d_ws;
        float*    partial = (float*)(pu + puN);   // 37 (padded to 64)
        float*    resp    = partial + 64;         // 512
        actloss_k1<<<NGR, NTH1, 0, stream>>>(a, a2, pu, resp);
        actloss_k2<<<NJ,  NTH2, 0, stream>>>(pu, resp, partial);
        actloss_k3<<<1,   64,   0, stream>>>(partial, out);
    } else {
        float* part = (float*)d_ws;   // 750 floats
        actloss_col_kernel<<<TLEN, 256, 0, stream>>>(a, a2, part);
        actloss_fallback_reduce<<<1, 256, 0, stream>>>(part, out);
    }
}

// Round 14
// 19.063 us; speedup vs baseline: 1.2854x; 1.2854x over previous
//
#include <hip/hip_runtime.h>

#define BATCH  4096
#define TLEN   750
#define NK     6                 // pair offsets k=1..6 (k=0 contributes exactly 0)
#define WSTRIP 250               // owned columns per strip
#define NSTRIP 3                 // 3*250 = 750 exactly
#define NTH1   768               // 12 waves = 3 strips x 4 row-subsets
#define RSUB   4                 // row-subsets per block
#define NGR    256               // row-groups == K1 grid (1 block/CU, balanced)
#define RPB    (BATCH/NGR)       // 16 rows per block
#define RPW    (RPB/RSUB)        // 4 rows per wave
#define QSZ    (2*NK*256)        // 3072 floats per strip partial (LDS)
#define NJ     (NSTRIP*NK*2)     // 36 pair-slabs (strip, k, half)
#define NTH2   1024              // K2 block size

// ---------------- helpers ----------------

template<int NW>
__device__ __forceinline__ float block_reduce(float v, float* red) {
    #pragma unroll
    for (int off = 32; off > 0; off >>= 1) v += __shfl_down(v, off, 64);
    const int t = threadIdx.x;
    if ((t & 63) == 0) red[t >> 6] = v;
    __syncthreads();
    float r = 0.f;
    if (t == 0) {
        #pragma unroll
        for (int w = 0; w < NW; ++w) r += red[w];
    }
    __syncthreads();
    return r;
}

// pack two non-negative finite floats as bf16 pair (RNE-ish) into one u32
__device__ __forceinline__ unsigned pack2(float v1, float v2) {
    const unsigned b1 = (__float_as_uint(v1) + 0x8000u) >> 16;
    const unsigned b2 = (__float_as_uint(v2) + 0x8000u) >> 16;
    return (b1 << 16) | (b2 & 0xffffu);
}

// ---------------- K1: one balanced block per CU, 2-stage parity reduce ----------------
// Wave w: strip s = w%3, row-subset rw = w/3 (4 rows). Lane owns 4 cols via
// two float2 loads (even bases -> 8B aligned; min(...,748) clamps at array
// end). ALL 16 loads of the 4-row batch are issued before any dependent op.
// Neighborhood n[0..9]: 4 shuffles from lane+1, 2 from lane+2 per array.
// Garbage reaches only slots with strip-local q>=250 or i+k>749 -- K2 gates.
// Cross-subset reduce: waves rw=0,1 WRITE buf[s][rw]; barrier; rw=2,3 ADD
// into buf[s][rw-2]; barrier; tail sums buf[s][0]+buf[s][1] while packing.
// Partials stored TRANSPOSED + bf16-PACKED: pu[((s*12+2k+h)*NGR+g)*128 + idx].
__global__ __launch_bounds__(NTH1, 3) void actloss_k1(
        const float* __restrict__ a, const float* __restrict__ a2,
        unsigned* __restrict__ pu, float* __restrict__ resp) {
    const int t  = threadIdx.x;
    const int w  = t >> 6;
    const int l  = t & 63;
    const int s  = w % NSTRIP;
    const int rw = w / NSTRIP;
    const int g  = (int)blockIdx.x;

    const int colr = s * WSTRIP + 4 * l;
    const int bc0  = min(colr,     TLEN - 2);
    const int bc1  = min(colr + 2, TLEN - 2);

    float maskf[4];
    #pragma unroll
    for (int c = 0; c < 4; ++c) maskf[c] = (4 * l + c < WSTRIP) ? 1.f : 0.f;

    float s1[4][NK], s2[4][NK];
    #pragma unroll
    for (int c = 0; c < 4; ++c)
        #pragma unroll
        for (int k = 0; k < NK; ++k) { s1[c][k] = 0.f; s2[c][k] = 0.f; }
    float res = 0.f;

    const int r0 = g * RPB + rw * RPW;

    // ---- issue ALL loads of the 4-row batch up front (16 float2 in flight) --
    float2 A0[RPW], A1[RPW], B0[RPW], B1[RPW];
    #pragma unroll
    for (int r = 0; r < RPW; ++r) {
        const size_t off = (size_t)(r0 + r) * TLEN;
        A0[r] = *reinterpret_cast<const float2*>(a  + off + bc0);
        A1[r] = *reinterpret_cast<const float2*>(a  + off + bc1);
        B0[r] = *reinterpret_cast<const float2*>(a2 + off + bc0);
        B1[r] = *reinterpret_cast<const float2*>(a2 + off + bc1);
    }

    #pragma unroll
    for (int r = 0; r < RPW; ++r) {
        float n[10], m[10];
        n[0] = A0[r].x; n[1] = A0[r].y; n[2] = A1[r].x; n[3] = A1[r].y;
        m[0] = B0[r].x; m[1] = B0[r].y; m[2] = B1[r].x; m[3] = B1[r].y;
        #pragma unroll
        for (int j = 0; j < 4; ++j) {
            n[4 + j] = __shfl_down(n[j], 1, 64);
            m[4 + j] = __shfl_down(m[j], 1, 64);
        }
        n[8] = __shfl_down(n[0], 2, 64);  n[9] = __shfl_down(n[1], 2, 64);
        m[8] = __shfl_down(m[0], 2, 64);  m[9] = __shfl_down(m[1], 2, 64);

        #pragma unroll
        for (int c = 0; c < 4; ++c) {
            #pragma unroll
            for (int k = 1; k <= NK; ++k) {
                const float d = n[c] - n[c + k];
                s1[c][k - 1] = fmaf(d, d, s1[c][k - 1]);
                s2[c][k - 1] += fabsf(m[c] - m[c + k]);
            }
            const float rr = n[c] - m[c];
            res = fmaf(rr * rr, maskf[c], res);
        }
    }

    // ---- 2-stage parity reduce ----
    __shared__ float buf[NSTRIP][2][QSZ];    // 72 KB (1 block/CU)
    __shared__ float rwred[12];
    if (rw < 2) {
        #pragma unroll
        for (int k = 0; k < NK; ++k) {
            *reinterpret_cast<float4*>(&buf[s][rw][k * 256 + 4 * l]) =
                make_float4(s1[0][k], s1[1][k], s1[2][k], s1[3][k]);
            *reinterpret_cast<float4*>(&buf[s][rw][NK * 256 + k * 256 + 4 * l]) =
                make_float4(s2[0][k], s2[1][k], s2[2][k], s2[3][k]);
        }
    }
    #pragma unroll
    for (int off = 32; off > 0; off >>= 1) res += __shfl_down(res, off, 64);
    if (l == 0) rwred[w] = res;
    __syncthreads();
    if (rw >= 2) {
        const int pb = rw - 2;
        #pragma unroll
        for (int k = 0; k < NK; ++k) {
            float4* q1 = reinterpret_cast<float4*>(&buf[s][pb][k * 256 + 4 * l]);
            float4 v1 = *q1;
            v1.x += s1[0][k]; v1.y += s1[1][k]; v1.z += s1[2][k]; v1.w += s1[3][k];
            *q1 = v1;
            float4* q2 = reinterpret_cast<float4*>(&buf[s][pb][NK * 256 + k * 256 + 4 * l]);
            float4 v2 = *q2;
            v2.x += s2[0][k]; v2.y += s2[1][k]; v2.z += s2[2][k]; v2.w += s2[3][k];
            *q2 = v2;
        }
    }
    __syncthreads();

    // packed transposed store: 4608 u32 per block, 6 iterations
    for (int e = t; e < NSTRIP * NK * 256; e += NTH1) {
        const int si  = e / (NK * 256);
        const int rem = e % (NK * 256);
        const int k   = rem >> 8;
        const int col = rem & 255;
        const float S1 = buf[si][0][k * 256 + col] + buf[si][1][k * 256 + col];
        const float S2 = buf[si][0][NK * 256 + k * 256 + col]
                       + buf[si][1][NK * 256 + k * 256 + col];
        pu[((size_t)(si * 12 + (k << 1) + (col >> 7)) * NGR + g) * 128
           + (col & 127)] = pack2(S1, S2);
    }
    if (t == 0) {
        float rs = 0.f;
        #pragma unroll
        for (int i = 0; i < 12; ++i) rs += rwred[i];
        resp[g] = rs;
    }
}

// ---------------- K2: streaming packed g-sum + in-block finish ----------------
// Block j streams its contiguous 128 KB slab with uint4, unpacks bf16 pairs,
// accumulates f32, transposes via LDS, applies exp + closed-form weight:
//   base (k<=4 ? 2 : 1); +(6-k) at i=0; +(4-k) at i=749-k (k<=3).
// Block 0 additionally reduces the res partials into partial[36].
__global__ __launch_bounds__(NTH2) void actloss_k2(
        const unsigned* __restrict__ pu, const float* __restrict__ resp,
        float* __restrict__ partial) {
    const int t = threadIdx.x;
    const int j = (int)blockIdx.x;
    const uint4* slab = reinterpret_cast<const uint4*>(pu + (size_t)j * NGR * 128);

    const int cg    = t & 31;    // colgroup: cols 4cg..4cg+3
    const int gbase = t >> 5;    // 0..31

    float s1a[4] = {0.f, 0.f, 0.f, 0.f}, s2a[4] = {0.f, 0.f, 0.f, 0.f};
    #pragma unroll
    for (int pass = 0; pass < NGR / 32; ++pass) {          // 8 passes
        const uint4 v = slab[(size_t)(pass * 32 + gbase) * 32 + cg];
        const unsigned u[4] = {v.x, v.y, v.z, v.w};
        #pragma unroll
        for (int c = 0; c < 4; ++c) {
            s1a[c] += __uint_as_float(u[c] & 0xffff0000u);
            s2a[c] += __uint_as_float(u[c] << 16);
        }
    }

    __shared__ float smA[NTH2][5], smB[NTH2][5];   // pad 5: conflict-free writes
    __shared__ float red[16];
    #pragma unroll
    for (int c = 0; c < 4; ++c) { smA[t][c] = s1a[c]; smB[t][c] = s2a[c]; }
    __syncthreads();

    float acc = 0.f;
    if (t < 128) {
        float S1 = 0.f, S2 = 0.f;
        const int rcg = t >> 2, ci = t & 3;
        #pragma unroll
        for (int q = 0; q < 32; ++q) {
            S1 += smA[q * 32 + rcg][ci];
            S2 += smB[q * 32 + rcg][ci];
        }
        const int s  = j / 12;
        const int jj = j % 12;
        const int k1 = (jj >> 1) + 1;
        const int h  = jj & 1;
        const int col = h * 128 + t;
        const int i   = s * WSTRIP + col;
        if (col < WSTRIP && i + k1 <= TLEN - 1) {
            const float Tv = expf(-0.5f * S1) * S2;
            float wgt = (k1 <= 4) ? 2.f : 1.f;
            if (i == 0) wgt += (float)(6 - k1);
            if (k1 <= 3 && i == TLEN - 1 - k1) wgt += (float)(4 - k1);
            acc = wgt * Tv;
        }
    }
    const float r = block_reduce<16>(acc, red);
    if (t == 0) partial[j] = r;

    if (j == 0) {   // block-uniform: fold res reduction into K2
        const float ra = (t < NGR) ? resp[t] : 0.f;
        const float r2 = block_reduce<16>(ra, red);
        if (t == 0) partial[NJ] = r2;
    }
}

// ---------------- K3: single-wave scalar finish ----------------
__global__ __launch_bounds__(64) void actloss_k3(
        const float* __restrict__ partial, float* __restrict__ out) {
    const int t = threadIdx.x;
    float v = (t < NJ) ? partial[t] : 0.f;
    if (t == 0) v += 0.1f * partial[NJ];
    #pragma unroll
    for (int off = 32; off > 0; off >>= 1) v += __shfl_down(v, off, 64);
    if (t == 0) out[0] = v * (1.0f / (float)BATCH);
}

// ---------------- fallback slow path (round-1, known-good) ----------------

__global__ __launch_bounds__(256) void actloss_col_kernel(
        const float* __restrict__ a, const float* __restrict__ a2,
        float* __restrict__ part) {
    const int i = blockIdx.x;
    const int t = threadIdx.x;
    __shared__ float red[4];
    int cidx[11];
    #pragma unroll
    for (int j = 0; j < 11; ++j) {
        int c = i + j - 6;
        cidx[j] = c < 0 ? 0 : (c > TLEN - 1 ? TLEN - 1 : c);
    }
    float s1[11], s2[11];
    #pragma unroll
    for (int j = 0; j < 11; ++j) { s1[j] = 0.f; s2[j] = 0.f; }
    float resacc = 0.f;
    for (int b = t; b < BATCH; b += 256) {
        const float* arow  = a  + (size_t)b * TLEN;
        const float* a2row = a2 + (size_t)b * TLEN;
        const float ai = arow[i], a2i = a2row[i];
        const float r = ai - a2i;
        resacc = fmaf(r, r, resacc);
        #pragma unroll
        for (int j = 0; j < 11; ++j) {
            const float d = ai - arow[cidx[j]];
            s1[j] = fmaf(d, d, s1[j]);
            s2[j] += fabsf(a2i - a2row[cidx[j]]);
        }
    }
    float term = 0.f;
    #pragma unroll
    for (int j = 0; j < 11; ++j) {
        const float s1r = block_reduce<4>(s1[j], red);
        const float s2r = block_reduce<4>(s2[j], red);
        if (t == 0) term += expf(-0.5f * s1r) * s2r;
    }
    const float resr = block_reduce<4>(resacc, red);
    if (t == 0) part[i] = (term + 0.1f * resr) * (1.0f / (float)BATCH);
}

__global__ __launch_bounds__(256) void actloss_fallback_reduce(
        const float* __restrict__ part, float* __restrict__ out) {
    __shared__ float red[4];
    float v = 0.f;
    for (int k = threadIdx.x; k < TLEN; k += 256) v += part[k];
    const float r = block_reduce<4>(v, red);
    if (threadIdx.x == 0) out[0] = r;
}

// ---------------- launcher ----------------

extern "C" void kernel_launch(void* const* d_in, const int* in_sizes, int n_in,
                              void* d_out, int out_size, void* d_ws, size_t ws_size,
                              hipStream_t stream) {
    const float* a  = (const float*)d_in[0];   // actioness
    const float* a2 = (const float*)d_in[1];   // actioness_2
    float* out = (float*)d_out;

    const size_t puN  = (size_t)NJ * NGR * 128;       // 1,179,648 u32 (4.7 MB)
    const size_t need = (puN + 64 + NGR + 16) * 4;

    if (ws_size >= need) {
        unsigned* pu      = (unsigned*)d_ws;
        float*    partial = (float*)(pu + puN);   // 37 (padded to 64)
        float*    resp    = partial + 64;         // 256
        actloss_k1<<<NGR, NTH1, 0, stream>>>(a, a2, pu, resp);
        actloss_k2<<<NJ,  NTH2, 0, stream>>>(pu, resp, partial);
        actloss_k3<<<1,   64,   0, stream>>>(partial, out);
    } else {
        float* part = (float*)d_ws;   // 750 floats
        actloss_col_kernel<<<TLEN, 256, 0, stream>>>(a, a2, part);
        actloss_fallback_reduce<<<1, 256, 0, stream>>>(part, out);
    }
}

// Round 15
// 18.625 us; speedup vs baseline: 1.3157x; 1.0235x over previous
//
#include <hip/hip_runtime.h>

#define BATCH  4096
#define TLEN   750
#define NK     6                 // pair offsets k=1..6 (k=0 contributes exactly 0)
#define WSTRIP 250               // owned columns per strip
#define NSTRIP 3                 // 3*250 = 750 exactly
#define NTH1   768               // 12 waves = 3 strips x 4 row-subsets
#define RSUB   4                 // row-subsets per block
#define NGR    256               // row-groups == K1 grid (1 block/CU, balanced)
#define RPB    (BATCH/NGR)       // 16 rows per block
#define RPW    (RPB/RSUB)        // 4 rows per wave
#define QSZ    (2*NK*256)        // 3072 floats per strip partial (LDS)
#define NJ     (NSTRIP*NK*2)     // 36 pair-slabs (strip, k, half)
#define NTH2   1024              // K2 block size

typedef float v2f __attribute__((ext_vector_type(2)));

// ---------------- helpers ----------------

template<int NW>
__device__ __forceinline__ float block_reduce(float v, float* red) {
    #pragma unroll
    for (int off = 32; off > 0; off >>= 1) v += __shfl_down(v, off, 64);
    const int t = threadIdx.x;
    if ((t & 63) == 0) red[t >> 6] = v;
    __syncthreads();
    float r = 0.f;
    if (t == 0) {
        #pragma unroll
        for (int w = 0; w < NW; ++w) r += red[w];
    }
    __syncthreads();
    return r;
}

// pack two non-negative finite floats as bf16 pair (RNE-ish) into one u32
__device__ __forceinline__ unsigned pack2(float v1, float v2) {
    const unsigned b1 = (__float_as_uint(v1) + 0x8000u) >> 16;
    const unsigned b2 = (__float_as_uint(v2) + 0x8000u) >> 16;
    return (b1 << 16) | (b2 & 0xffffu);
}

__device__ __forceinline__ v2f v2shfl(v2f v, int d) {
    v2f r;
    r.x = __shfl_down(v.x, d, 64);
    r.y = __shfl_down(v.y, d, 64);
    return r;
}

__device__ __forceinline__ v2f v2abs(v2f v) {
    v2f r;
    r.x = __builtin_fabsf(v.x);
    r.y = __builtin_fabsf(v.y);
    return r;
}

// ---------------- K1: one balanced block per CU, packed-f32 inner loop ----------------
// Wave w: strip s = w%3, row-subset rw = w/3 (4 rows). Lane owns 4 cols via
// two v2f loads (even bases -> 8B aligned; min(...,748) clamps at array end).
// ALL 16 loads of the 4-row batch are issued before any dependent op.
// Pair registers: n2[0..4] = cols (0,1)(2,3)(4,5)(6,7)(8,9); n2s[p] = shifted
// pairs (2p+1, 2p+2) -> every k has ALIGNED float2 operands:
//   even k: y = n2[p + k/2];  odd k: y = n2s[p + (k-1)/2]
// so s1 = pk_sub+pk_fma, s2 = pk_sub+abs+pk_add (VOP3P packed f32).
// Garbage reaches only slots with strip-local q>=250 or i+k>749 -- K2 gates.
// Cross-subset reduce: 2-stage parity (rw<2 write, rw>=2 add, tail folds +).
// Partials stored TRANSPOSED + bf16-PACKED: pu[((s*12+2k+h)*NGR+g)*128 + idx].
__global__ __launch_bounds__(NTH1, 3) void actloss_k1(
        const float* __restrict__ a, const float* __restrict__ a2,
        unsigned* __restrict__ pu, float* __restrict__ resp) {
    const int t  = threadIdx.x;
    const int w  = t >> 6;
    const int l  = t & 63;
    const int s  = w % NSTRIP;
    const int rw = w / NSTRIP;
    const int g  = (int)blockIdx.x;

    const int colr = s * WSTRIP + 4 * l;
    const int bc0  = min(colr,     TLEN - 2);
    const int bc1  = min(colr + 2, TLEN - 2);

    v2f mv[2];
    mv[0].x = (4 * l + 0 < WSTRIP) ? 1.f : 0.f;
    mv[0].y = (4 * l + 1 < WSTRIP) ? 1.f : 0.f;
    mv[1].x = (4 * l + 2 < WSTRIP) ? 1.f : 0.f;
    mv[1].y = (4 * l + 3 < WSTRIP) ? 1.f : 0.f;

    v2f s1v[2][NK], s2v[2][NK];
    #pragma unroll
    for (int p = 0; p < 2; ++p)
        #pragma unroll
        for (int k = 0; k < NK; ++k) { s1v[p][k] = (v2f)(0.f); s2v[p][k] = (v2f)(0.f); }
    v2f resv[2] = {(v2f)(0.f), (v2f)(0.f)};

    const int r0 = g * RPB + rw * RPW;

    // ---- issue ALL loads of the 4-row batch up front (16 v2f in flight) ----
    v2f A0[RPW], A1[RPW], B0[RPW], B1[RPW];
    #pragma unroll
    for (int r = 0; r < RPW; ++r) {
        const size_t off = (size_t)(r0 + r) * TLEN;
        A0[r] = *reinterpret_cast<const v2f*>(a  + off + bc0);
        A1[r] = *reinterpret_cast<const v2f*>(a  + off + bc1);
        B0[r] = *reinterpret_cast<const v2f*>(a2 + off + bc0);
        B1[r] = *reinterpret_cast<const v2f*>(a2 + off + bc1);
    }

    #pragma unroll
    for (int r = 0; r < RPW; ++r) {
        v2f n2[5], m2[5];
        n2[0] = A0[r]; n2[1] = A1[r];
        m2[0] = B0[r]; m2[1] = B1[r];
        n2[2] = v2shfl(n2[0], 1);  n2[3] = v2shfl(n2[1], 1);  n2[4] = v2shfl(n2[0], 2);
        m2[2] = v2shfl(m2[0], 1);  m2[3] = v2shfl(m2[1], 1);  m2[4] = v2shfl(m2[0], 2);

        // shifted pair arrays: n2s[p] = (n[2p+1], n[2p+2])
        v2f n2s[4], m2s[4];
        #pragma unroll
        for (int p = 0; p < 4; ++p) {
            n2s[p].x = n2[p].y;  n2s[p].y = n2[p + 1].x;
            m2s[p].x = m2[p].y;  m2s[p].y = m2[p + 1].x;
        }

        #pragma unroll
        for (int k = 1; k <= NK; ++k) {
            #pragma unroll
            for (int p = 0; p < 2; ++p) {
                const v2f yn = (k & 1) ? n2s[p + ((k - 1) >> 1)] : n2[p + (k >> 1)];
                const v2f ym = (k & 1) ? m2s[p + ((k - 1) >> 1)] : m2[p + (k >> 1)];
                const v2f d  = n2[p] - yn;
                s1v[p][k - 1] += d * d;                 // pk_fma
                s2v[p][k - 1] += v2abs(m2[p] - ym);     // pk_add + abs + pk_add
            }
        }
        #pragma unroll
        for (int p = 0; p < 2; ++p) {
            const v2f rr = n2[p] - m2[p];
            resv[p] += (rr * mv[p]) * rr;               // masked squared residual
        }
    }

    float res = (resv[0].x + resv[0].y) + (resv[1].x + resv[1].y);

    // ---- 2-stage parity reduce ----
    __shared__ float buf[NSTRIP][2][QSZ];    // 72 KB (1 block/CU)
    __shared__ float rwred[12];
    if (rw < 2) {
        #pragma unroll
        for (int k = 0; k < NK; ++k) {
            *reinterpret_cast<float4*>(&buf[s][rw][k * 256 + 4 * l]) =
                make_float4(s1v[0][k].x, s1v[0][k].y, s1v[1][k].x, s1v[1][k].y);
            *reinterpret_cast<float4*>(&buf[s][rw][NK * 256 + k * 256 + 4 * l]) =
                make_float4(s2v[0][k].x, s2v[0][k].y, s2v[1][k].x, s2v[1][k].y);
        }
    }
    #pragma unroll
    for (int off = 32; off > 0; off >>= 1) res += __shfl_down(res, off, 64);
    if (l == 0) rwred[w] = res;
    __syncthreads();
    if (rw >= 2) {
        const int pb = rw - 2;
        #pragma unroll
        for (int k = 0; k < NK; ++k) {
            float4* q1 = reinterpret_cast<float4*>(&buf[s][pb][k * 256 + 4 * l]);
            float4 v1 = *q1;
            v1.x += s1v[0][k].x; v1.y += s1v[0][k].y;
            v1.z += s1v[1][k].x; v1.w += s1v[1][k].y;
            *q1 = v1;
            float4* q2 = reinterpret_cast<float4*>(&buf[s][pb][NK * 256 + k * 256 + 4 * l]);
            float4 v2 = *q2;
            v2.x += s2v[0][k].x; v2.y += s2v[0][k].y;
            v2.z += s2v[1][k].x; v2.w += s2v[1][k].y;
            *q2 = v2;
        }
    }
    __syncthreads();

    // packed transposed store: 4608 u32 per block, 6 iterations
    for (int e = t; e < NSTRIP * NK * 256; e += NTH1) {
        const int si  = e / (NK * 256);
        const int rem = e % (NK * 256);
        const int k   = rem >> 8;
        const int col = rem & 255;
        const float S1 = buf[si][0][k * 256 + col] + buf[si][1][k * 256 + col];
        const float S2 = buf[si][0][NK * 256 + k * 256 + col]
                       + buf[si][1][NK * 256 + k * 256 + col];
        pu[((size_t)(si * 12 + (k << 1) + (col >> 7)) * NGR + g) * 128
           + (col & 127)] = pack2(S1, S2);
    }
    if (t == 0) {
        float rs = 0.f;
        #pragma unroll
        for (int i = 0; i < 12; ++i) rs += rwred[i];
        resp[g] = rs;
    }
}

// ---------------- K2: streaming packed g-sum + in-block finish ----------------
// Block j streams its contiguous 128 KB slab with uint4, unpacks bf16 pairs,
// accumulates f32, transposes via LDS, applies exp + closed-form weight:
//   base (k<=4 ? 2 : 1); +(6-k) at i=0; +(4-k) at i=749-k (k<=3).
// Block 0 additionally reduces the res partials into partial[36].
__global__ __launch_bounds__(NTH2) void actloss_k2(
        const unsigned* __restrict__ pu, const float* __restrict__ resp,
        float* __restrict__ partial) {
    const int t = threadIdx.x;
    const int j = (int)blockIdx.x;
    const uint4* slab = reinterpret_cast<const uint4*>(pu + (size_t)j * NGR * 128);

    const int cg    = t & 31;    // colgroup: cols 4cg..4cg+3
    const int gbase = t >> 5;    // 0..31

    float s1a[4] = {0.f, 0.f, 0.f, 0.f}, s2a[4] = {0.f, 0.f, 0.f, 0.f};
    #pragma unroll
    for (int pass = 0; pass < NGR / 32; ++pass) {          // 8 passes
        const uint4 v = slab[(size_t)(pass * 32 + gbase) * 32 + cg];
        const unsigned u[4] = {v.x, v.y, v.z, v.w};
        #pragma unroll
        for (int c = 0; c < 4; ++c) {
            s1a[c] += __uint_as_float(u[c] & 0xffff0000u);
            s2a[c] += __uint_as_float(u[c] << 16);
        }
    }

    __shared__ float smA[NTH2][5], smB[NTH2][5];   // pad 5: conflict-free writes
    __shared__ float red[16];
    #pragma unroll
    for (int c = 0; c < 4; ++c) { smA[t][c] = s1a[c]; smB[t][c] = s2a[c]; }
    __syncthreads();

    float acc = 0.f;
    if (t < 128) {
        float S1 = 0.f, S2 = 0.f;
        const int rcg = t >> 2, ci = t & 3;
        #pragma unroll
        for (int q = 0; q < 32; ++q) {
            S1 += smA[q * 32 + rcg][ci];
            S2 += smB[q * 32 + rcg][ci];
        }
        const int s  = j / 12;
        const int jj = j % 12;
        const int k1 = (jj >> 1) + 1;
        const int h  = jj & 1;
        const int col = h * 128 + t;
        const int i   = s * WSTRIP + col;
        if (col < WSTRIP && i + k1 <= TLEN - 1) {
            const float Tv = expf(-0.5f * S1) * S2;
            float wgt = (k1 <= 4) ? 2.f : 1.f;
            if (i == 0) wgt += (float)(6 - k1);
            if (k1 <= 3 && i == TLEN - 1 - k1) wgt += (float)(4 - k1);
            acc = wgt * Tv;
        }
    }
    const float r = block_reduce<16>(acc, red);
    if (t == 0) partial[j] = r;

    if (j == 0) {   // block-uniform: fold res reduction into K2
        const float ra = (t < NGR) ? resp[t] : 0.f;
        const float r2 = block_reduce<16>(ra, red);
        if (t == 0) partial[NJ] = r2;
    }
}

// ---------------- K3: single-wave scalar finish ----------------
__global__ __launch_bounds__(64) void actloss_k3(
        const float* __restrict__ partial, float* __restrict__ out) {
    const int t = threadIdx.x;
    float v = (t < NJ) ? partial[t] : 0.f;
    if (t == 0) v += 0.1f * partial[NJ];
    #pragma unroll
    for (int off = 32; off > 0; off >>= 1) v += __shfl_down(v, off, 64);
    if (t == 0) out[0] = v * (1.0f / (float)BATCH);
}

// ---------------- fallback slow path (round-1, known-good) ----------------

__global__ __launch_bounds__(256) void actloss_col_kernel(
        const float* __restrict__ a, const float* __restrict__ a2,
        float* __restrict__ part) {
    const int i = blockIdx.x;
    const int t = threadIdx.x;
    __shared__ float red[4];
    int cidx[11];
    #pragma unroll
    for (int j = 0; j < 11; ++j) {
        int c = i + j - 6;
        cidx[j] = c < 0 ? 0 : (c > TLEN - 1 ? TLEN - 1 : c);
    }
    float s1[11], s2[11];
    #pragma unroll
    for (int j = 0; j < 11; ++j) { s1[j] = 0.f; s2[j] = 0.f; }
    float resacc = 0.f;
    for (int b = t; b < BATCH; b += 256) {
        const float* arow  = a  + (size_t)b * TLEN;
        const float* a2row = a2 + (size_t)b * TLEN;
        const float ai = arow[i], a2i = a2row[i];
        const float r = ai - a2i;
        resacc = fmaf(r, r, resacc);
        #pragma unroll
        for (int j = 0; j < 11; ++j) {
            const float d = ai - arow[cidx[j]];
            s1[j] = fmaf(d, d, s1[j]);
            s2[j] += fabsf(a2i - a2row[cidx[j]]);
        }
    }
    float term = 0.f;
    #pragma unroll
    for (int j = 0; j < 11; ++j) {
        const float s1r = block_reduce<4>(s1[j], red);
        const float s2r = block_reduce<4>(s2[j], red);
        if (t == 0) term += expf(-0.5f * s1r) * s2r;
    }
    const float resr = block_reduce<4>(resacc, red);
    if (t == 0) part[i] = (term + 0.1f * resr) * (1.0f / (float)BATCH);
}

__global__ __launch_bounds__(256) void actloss_fallback_reduce(
        const float* __restrict__ part, float* __restrict__ out) {
    __shared__ float red[4];
    float v = 0.f;
    for (int k = threadIdx.x; k < TLEN; k += 256) v += part[k];
    const float r = block_reduce<4>(v, red);
    if (threadIdx.x == 0) out[0] = r;
}

// ---------------- launcher ----------------

extern "C" void kernel_launch(void* const* d_in, const int* in_sizes, int n_in,
                              void* d_out, int out_size, void* d_ws, size_t ws_size,
                              hipStream_t stream) {
    const float* a  = (const float*)d_in[0];   // actioness
    const float* a2 = (const float*)d_in[1];   // actioness_2
    float* out = (float*)d_out;

    const size_t puN  = (size_t)NJ * NGR * 128;       // 1,179,648 u32 (4.7 MB)
    const size_t need = (puN + 64 + NGR + 16) * 4;

    if (ws_size >= need) {
        unsigned* pu      = (unsigned*)d_ws;
        float*    partial = (float*)(pu + puN);   // 37 (padded to 64)
        float*    resp    = partial + 64;         // 256
        actloss_k1<<<NGR, NTH1, 0, stream>>>(a, a2, pu, resp);
        actloss_k2<<<NJ,  NTH2, 0, stream>>>(pu, resp, partial);
        actloss_k3<<<1,   64,   0, stream>>>(partial, out);
    } else {
        float* part = (float*)d_ws;   // 750 floats
        actloss_col_kernel<<<TLEN, 256, 0, stream>>>(a, a2, part);
        actloss_fallback_reduce<<<1, 256, 0, stream>>>(part, out);
    }
}